// Round 8
// baseline (65.127 us; speedup 1.0000x reference)
//
#include <hip/hip_runtime.h>
#include <hip/hip_fp16.h>

#define HH 512
#define WW 512
#define BB 8
#define HW (HH * WW)
#define DXS 0.5f
#define NSTEPS 8

#define R_BLK 4          // trajectory rows per block
#define BAND 15          // staged rows per field
#define LSW 512          // LDS row stride in u32: stride % 32 == 0 -> bank = x%32,
                         // contiguous-x lanes are conflict-free (520 caused 8*dr shifts)

typedef float f2  __attribute__((ext_vector_type(2)));
typedef float f4a __attribute__((ext_vector_type(4)));
typedef unsigned int u4a __attribute__((ext_vector_type(4)));

__device__ __forceinline__ f2 h2f(unsigned int h) {
    __half2 v = __builtin_bit_cast(__half2, h);
    float2 f = __half22float2(v);
    return (f2){f.x, f.y};
}
__device__ __forceinline__ unsigned int f2h(float a, float b) {
    __half2 h = __floats2half2_rn(a, b);
    return __builtin_bit_cast(unsigned int, h);
}

// bilinear from LDS half2 band (packed-fp16 lerps), rare global-f32 fallback
__device__ __forceinline__ f2 bilin_lds(const unsigned int* __restrict__ lds,
                                        int band_lo,
                                        const float* __restrict__ g0,
                                        const float* __restrict__ g1,
                                        float px, float py) {
    float x = fminf(fmaxf(px, 0.0f), (float)(WW - 1));
    float y = fminf(fmaxf(py, 0.0f), (float)(HH - 1));
    float x0f = fminf(floorf(x), (float)(WW - 2));
    float y0f = fminf(floorf(y), (float)(HH - 2));
    float wx = x - x0f;
    float wy = y - y0f;
    int xi = (int)x0f;
    int yi = (int)y0f;
    int r = yi - band_lo;
    f2 out;
    if ((unsigned)r <= (unsigned)(BAND - 2)) {
        int idx = (r << 9) + xi;            // r*512 + xi
        __half2 v00 = __builtin_bit_cast(__half2, lds[idx]);
        __half2 v01 = __builtin_bit_cast(__half2, lds[idx + 1]);
        __half2 v10 = __builtin_bit_cast(__half2, lds[idx + LSW]);
        __half2 v11 = __builtin_bit_cast(__half2, lds[idx + LSW + 1]);
        __half2 wxh = __float2half2_rn(wx);
        __half2 wyh = __float2half2_rn(wy);
        __half2 top = __hfma2(wxh, __hsub2(v01, v00), v00);
        __half2 bot = __hfma2(wxh, __hsub2(v11, v10), v10);
        __half2 o   = __hfma2(wyh, __hsub2(bot, top), top);
        float2 f = __half22float2(o);
        out = (f2){f.x, f.y};
    } else {
        int i00 = yi * WW + xi;
        float w00 = (1.0f - wx) * (1.0f - wy);
        float w01 = wx * (1.0f - wy);
        float w10 = (1.0f - wx) * wy;
        float w11 = wx * wy;
        out.x = g0[i00] * w00 + g0[i00 + 1] * w01 + g0[i00 + WW] * w10 + g0[i00 + WW + 1] * w11;
        out.y = g1[i00] * w00 + g1[i00 + 1] * w01 + g1[i00 + WW] * w10 + g1[i00 + WW + 1] * w11;
    }
    return out;
}

__global__ __launch_bounds__(256) void ivp_loss_lds(const float* __restrict__ vf_pred,
                                                    const float* __restrict__ vf_true,
                                                    double* __restrict__ acc,
                                                    unsigned int* __restrict__ cnt,
                                                    float* __restrict__ out,
                                                    int nblocks) {
    __shared__ unsigned int lt[BAND * LSW];   // true field, half2/px
    __shared__ unsigned int lp[BAND * LSW];   // pred field, half2/px
    __shared__ float wsum[4];

    int b    = blockIdx.x & 7;               // XCD-batch affinity
    int rb   = blockIdx.x >> 3;              // 0..127
    int base = rb * R_BLK;
    int band_lo = min(max(base - 5, 0), HH - BAND);

    const float* tg0 = vf_true + (size_t)b * 2 * HW;
    const float* tg1 = tg0 + HW;
    const float* pg0 = vf_pred + (size_t)b * 2 * HW;
    const float* pg1 = pg0 + HW;

    // ---- stage BAND rows of both fields into LDS as half2, coalesced ----
    for (int i = threadIdx.x; i < BAND * 128; i += 256) {
        int rl = i >> 7;                     // 0..14
        int g  = i & 127;                    // 4-px group
        int off = (band_lo + rl) * WW + g * 4;
        f4a tx = *(const f4a*)(tg0 + off);
        f4a ty = *(const f4a*)(tg1 + off);
        f4a px = *(const f4a*)(pg0 + off);
        f4a py = *(const f4a*)(pg1 + off);
        u4a wt = { f2h(tx.x, ty.x), f2h(tx.y, ty.y), f2h(tx.z, ty.z), f2h(tx.w, ty.w) };
        u4a wp = { f2h(px.x, py.x), f2h(px.y, py.y), f2h(px.z, py.z), f2h(px.w, py.w) };
        *(u4a*)&lt[rl * LSW + g * 4] = wt;
        *(u4a*)&lp[rl * LSW + g * 4] = wp;
    }
    __syncthreads();

    // ---- per-thread: 8 chains (wave owns one row; x = lane + 64c) ----
    int lane = threadIdx.x & 63;
    int wv   = threadIdx.x >> 6;
    int row  = base + wv;
    float fy = (float)row;

    float ptx[8], pty[8], ppx[8], ppy[8];
    float sum = 0.0f;

    // step 1: exact integer grid -> direct LDS reads
    #pragma unroll
    for (int c = 0; c < 8; ++c) {
        int x  = lane + 64 * c;
        int li = (row - band_lo) * LSW + x;
        f2 vt = h2f(lt[li]);
        f2 vp = h2f(lp[li]);
        float fx = (float)x;
        ptx[c] = fmaf(DXS, vt.x, fx);  pty[c] = fmaf(DXS, vt.y, fy);
        ppx[c] = fmaf(DXS, vp.x, fx);  ppy[c] = fmaf(DXS, vp.y, fy);
        float dx = ptx[c] - ppx[c], dy = pty[c] - ppy[c];
        sum += dx * dx + dy * dy;
    }

    // steps 2..8: LDS gathers
    #pragma unroll 1
    for (int s = 1; s < NSTEPS; ++s) {
        #pragma unroll
        for (int c = 0; c < 8; ++c) {
            f2 vt = bilin_lds(lt, band_lo, tg0, tg1, ptx[c], pty[c]);
            f2 vp = bilin_lds(lp, band_lo, pg0, pg1, ppx[c], ppy[c]);
            ptx[c] += DXS * vt.x;  pty[c] += DXS * vt.y;
            ppx[c] += DXS * vp.x;  ppy[c] += DXS * vp.y;
            float dx = ptx[c] - ppx[c], dy = pty[c] - ppy[c];
            sum += dx * dx + dy * dy;
        }
    }

    // ---- reduce + fused finalize ----
    for (int off = 32; off > 0; off >>= 1)
        sum += __shfl_down(sum, off, 64);
    if (lane == 0) wsum[wv] = sum;
    __syncthreads();
    if (threadIdx.x == 0) {
        double blocksum = (double)wsum[0] + (double)wsum[1]
                        + (double)wsum[2] + (double)wsum[3];
        atomicAdd(acc, blocksum);
        __threadfence();
        unsigned int done = atomicAdd(cnt, 1u);
        if (done == (unsigned)(nblocks - 1)) {
            double total = atomicAdd(acc, 0.0);   // device-scope read-back
            const double n = (double)(NSTEPS + 1) * BB * 2 * HW;
            out[0] = (float)(total / n);
        }
    }
}

extern "C" void kernel_launch(void* const* d_in, const int* in_sizes, int n_in,
                              void* d_out, int out_size, void* d_ws, size_t ws_size,
                              hipStream_t stream) {
    const float* vf_pred = (const float*)d_in[0];
    const float* vf_true = (const float*)d_in[1];
    float* out = (float*)d_out;
    double* acc = (double*)d_ws;
    unsigned int* cnt = (unsigned int*)((char*)d_ws + 8);

    hipMemsetAsync(d_ws, 0, 16, stream);

    int blocks = BB * (HH / R_BLK);          // 1024
    ivp_loss_lds<<<blocks, 256, 0, stream>>>(vf_pred, vf_true, acc, cnt, out, blocks);
}

// Round 9
// 51.125 us; speedup vs baseline: 1.2739x; 1.2739x over previous
//
#include <hip/hip_runtime.h>
#include <hip/hip_fp16.h>

#define HH 512
#define WW 512
#define BB 8
#define HW (HH * WW)
#define DXS 0.5f
#define NSTEPS 8

#define R_BLK 8          // trajectory rows per block (one per wave, 512 threads)
#define BAND 19          // staged rows per field (rows base-5 .. base+13)
#define LSW 512          // LDS row stride in u32

typedef float f2  __attribute__((ext_vector_type(2)));
typedef float f4a __attribute__((ext_vector_type(4)));
typedef unsigned int u4a __attribute__((ext_vector_type(4)));

__device__ __forceinline__ f2 h2f(unsigned int h) {
    __half2 v = __builtin_bit_cast(__half2, h);
    float2 f = __half22float2(v);
    return (f2){f.x, f.y};
}
__device__ __forceinline__ unsigned int f2h(float a, float b) {
    __half2 h = __floats2half2_rn(a, b);
    return __builtin_bit_cast(unsigned int, h);
}

// bilinear from LDS half2 band (f32 lerps), rare global-f32 fallback
__device__ __forceinline__ f2 bilin_lds(const unsigned int* __restrict__ lds,
                                        int band_lo,
                                        const float* __restrict__ g0,
                                        const float* __restrict__ g1,
                                        float px, float py) {
    float x = fminf(fmaxf(px, 0.0f), (float)(WW - 1));
    float y = fminf(fmaxf(py, 0.0f), (float)(HH - 1));
    float x0f = fminf(floorf(x), (float)(WW - 2));
    float y0f = fminf(floorf(y), (float)(HH - 2));
    float wx = x - x0f;
    float wy = y - y0f;
    int xi = (int)x0f;
    int yi = (int)y0f;
    int r = yi - band_lo;
    f2 out;
    if ((unsigned)r <= (unsigned)(BAND - 2)) {
        int idx = (r << 9) + xi;            // r*LSW + xi
        f2 v00 = h2f(lds[idx]);
        f2 v01 = h2f(lds[idx + 1]);
        f2 v10 = h2f(lds[idx + LSW]);
        f2 v11 = h2f(lds[idx + LSW + 1]);
        f2 top = v00 + wx * (v01 - v00);
        f2 bot = v10 + wx * (v11 - v10);
        out = top + wy * (bot - top);
    } else {
        int i00 = yi * WW + xi;
        float w00 = (1.0f - wx) * (1.0f - wy);
        float w01 = wx * (1.0f - wy);
        float w10 = (1.0f - wx) * wy;
        float w11 = wx * wy;
        out.x = g0[i00] * w00 + g0[i00 + 1] * w01 + g0[i00 + WW] * w10 + g0[i00 + WW + 1] * w11;
        out.y = g1[i00] * w00 + g1[i00 + 1] * w01 + g1[i00 + WW] * w10 + g1[i00 + WW + 1] * w11;
    }
    return out;
}

__global__ __launch_bounds__(512, 4) void ivp_loss_lds(const float* __restrict__ vf_pred,
                                                       const float* __restrict__ vf_true,
                                                       double* __restrict__ acc,
                                                       unsigned int* __restrict__ cnt,
                                                       float* __restrict__ out,
                                                       int nblocks) {
    __shared__ unsigned int lt[BAND * LSW];   // true field, half2/px  (38 KiB)
    __shared__ unsigned int lp[BAND * LSW];   // pred field, half2/px  (38 KiB)
    __shared__ float wsum[8];

    int b    = blockIdx.x & 7;               // XCD-batch affinity
    int rb   = blockIdx.x >> 3;              // 0..63
    int base = rb * R_BLK;
    int band_lo = min(max(base - 5, 0), HH - BAND);

    const float* tg0 = vf_true + (size_t)b * 2 * HW;
    const float* tg1 = tg0 + HW;
    const float* pg0 = vf_pred + (size_t)b * 2 * HW;
    const float* pg1 = pg0 + HW;

    // ---- stage BAND rows of both fields into LDS as half2, coalesced ----
    for (int i = threadIdx.x; i < BAND * 128; i += 512) {
        int rl = i >> 7;                     // 0..18
        int g  = i & 127;                    // 4-px group
        int off = (band_lo + rl) * WW + g * 4;
        f4a tx = *(const f4a*)(tg0 + off);
        f4a ty = *(const f4a*)(tg1 + off);
        f4a px = *(const f4a*)(pg0 + off);
        f4a py = *(const f4a*)(pg1 + off);
        u4a wt = { f2h(tx.x, ty.x), f2h(tx.y, ty.y), f2h(tx.z, ty.z), f2h(tx.w, ty.w) };
        u4a wp = { f2h(px.x, py.x), f2h(px.y, py.y), f2h(px.z, py.z), f2h(px.w, py.w) };
        *(u4a*)&lt[rl * LSW + g * 4] = wt;
        *(u4a*)&lp[rl * LSW + g * 4] = wp;
    }
    __syncthreads();

    // ---- per-thread: 8 chains (wave owns one row; x = lane + 64c) ----
    int lane = threadIdx.x & 63;
    int wv   = threadIdx.x >> 6;             // 0..7
    int row  = base + wv;
    float fy = (float)row;

    float ptx[8], pty[8], ppx[8], ppy[8];
    float sum = 0.0f;

    // step 1: exact integer grid -> direct LDS reads
    #pragma unroll
    for (int c = 0; c < 8; ++c) {
        int x  = lane + 64 * c;
        int li = (row - band_lo) * LSW + x;
        f2 vt = h2f(lt[li]);
        f2 vp = h2f(lp[li]);
        float fx = (float)x;
        ptx[c] = fmaf(DXS, vt.x, fx);  pty[c] = fmaf(DXS, vt.y, fy);
        ppx[c] = fmaf(DXS, vp.x, fx);  ppy[c] = fmaf(DXS, vp.y, fy);
        float dx = ptx[c] - ppx[c], dy = pty[c] - ppy[c];
        sum += dx * dx + dy * dy;
    }

    // steps 2..8: LDS gathers
    #pragma unroll 1
    for (int s = 1; s < NSTEPS; ++s) {
        #pragma unroll
        for (int c = 0; c < 8; ++c) {
            f2 vt = bilin_lds(lt, band_lo, tg0, tg1, ptx[c], pty[c]);
            f2 vp = bilin_lds(lp, band_lo, pg0, pg1, ppx[c], ppy[c]);
            ptx[c] += DXS * vt.x;  pty[c] += DXS * vt.y;
            ppx[c] += DXS * vp.x;  ppy[c] += DXS * vp.y;
            float dx = ptx[c] - ppx[c], dy = pty[c] - ppy[c];
            sum += dx * dx + dy * dy;
        }
    }

    // ---- reduce + fused finalize ----
    for (int off = 32; off > 0; off >>= 1)
        sum += __shfl_down(sum, off, 64);
    if (lane == 0) wsum[wv] = sum;
    __syncthreads();
    if (threadIdx.x == 0) {
        double blocksum = 0.0;
        #pragma unroll
        for (int w = 0; w < 8; ++w) blocksum += (double)wsum[w];
        atomicAdd(acc, blocksum);
        __threadfence();
        unsigned int done = atomicAdd(cnt, 1u);
        if (done == (unsigned)(nblocks - 1)) {
            double total = atomicAdd(acc, 0.0);   // device-scope read-back
            const double n = (double)(NSTEPS + 1) * BB * 2 * HW;
            out[0] = (float)(total / n);
        }
    }
}

extern "C" void kernel_launch(void* const* d_in, const int* in_sizes, int n_in,
                              void* d_out, int out_size, void* d_ws, size_t ws_size,
                              hipStream_t stream) {
    const float* vf_pred = (const float*)d_in[0];
    const float* vf_true = (const float*)d_in[1];
    float* out = (float*)d_out;
    double* acc = (double*)d_ws;
    unsigned int* cnt = (unsigned int*)((char*)d_ws + 8);

    hipMemsetAsync(d_ws, 0, 16, stream);

    int blocks = BB * (HH / R_BLK);          // 8 * 64 = 512
    ivp_loss_lds<<<blocks, 512, 0, stream>>>(vf_pred, vf_true, acc, cnt, out, blocks);
}

// Round 10
// 49.630 us; speedup vs baseline: 1.3123x; 1.0301x over previous
//
#include <hip/hip_runtime.h>
#include <hip/hip_fp16.h>

#define HH 512
#define WW 512
#define BB 8
#define HW (HH * WW)
#define DXS 0.5f
#define NSTEPS 8

#define R_BLK 8          // trajectory rows per block (one per wave, 512 threads)
#define BAND 19          // staged rows per field (rows base-5 .. base+13)
#define LSW 512          // LDS row stride in u32

#define XCLAMP 510.99997f   // <= nextafter(511)-: floor() <= 510, no second min needed

typedef float f2  __attribute__((ext_vector_type(2)));
typedef float f4a __attribute__((ext_vector_type(4)));
typedef unsigned int u4a __attribute__((ext_vector_type(4)));
typedef unsigned int u2l __attribute__((ext_vector_type(2), aligned(4)));  // -> ds_read2_b32

__device__ __forceinline__ f2 h2f(unsigned int h) {
    __half2 v = __builtin_bit_cast(__half2, h);
    float2 f = __half22float2(v);
    return (f2){f.x, f.y};
}
__device__ __forceinline__ unsigned int f2h(float a, float b) {
    __half2 h = __floats2half2_rn(a, b);
    return __builtin_bit_cast(unsigned int, h);
}

// bilinear from LDS half2 band (f32 lerps, paired ds_read2_b32), rare global fallback
__device__ __forceinline__ f2 bilin_lds(const unsigned int* __restrict__ lds,
                                        int band_lo,
                                        const float* __restrict__ g0,
                                        const float* __restrict__ g1,
                                        float px, float py) {
    float x = fminf(fmaxf(px, 0.0f), XCLAMP);    // v_med3_f32
    float y = fminf(fmaxf(py, 0.0f), XCLAMP);
    float x0f = floorf(x);                        // <= 510 by clamp
    float y0f = floorf(y);
    float wx = x - x0f;
    float wy = y - y0f;
    int xi = (int)x0f;
    int yi = (int)y0f;
    int r = yi - band_lo;
    f2 out;
    if ((unsigned)r <= (unsigned)(BAND - 2)) {
        int idx = (r << 9) + xi;                  // r*LSW + xi
        u2l tw = *(const u2l*)&lds[idx];          // ds_read2_b32 offset0:0 offset1:1
        u2l bw = *(const u2l*)&lds[idx + LSW];
        f2 v00 = h2f(tw.x), v01 = h2f(tw.y);
        f2 v10 = h2f(bw.x), v11 = h2f(bw.y);
        f2 top = v00 + wx * (v01 - v00);
        f2 bot = v10 + wx * (v11 - v10);
        out = top + wy * (bot - top);
    } else {
        int i00 = yi * WW + xi;
        float w00 = (1.0f - wx) * (1.0f - wy);
        float w01 = wx * (1.0f - wy);
        float w10 = (1.0f - wx) * wy;
        float w11 = wx * wy;
        out.x = g0[i00] * w00 + g0[i00 + 1] * w01 + g0[i00 + WW] * w10 + g0[i00 + WW + 1] * w11;
        out.y = g1[i00] * w00 + g1[i00 + 1] * w01 + g1[i00 + WW] * w10 + g1[i00 + WW + 1] * w11;
    }
    return out;
}

__global__ __launch_bounds__(512, 4) void ivp_loss_lds(const float* __restrict__ vf_pred,
                                                       const float* __restrict__ vf_true,
                                                       double* __restrict__ acc,
                                                       unsigned int* __restrict__ cnt,
                                                       float* __restrict__ out,
                                                       int nblocks) {
    __shared__ unsigned int lt[BAND * LSW];   // true field, half2/px  (38 KiB)
    __shared__ unsigned int lp[BAND * LSW];   // pred field, half2/px  (38 KiB)
    __shared__ float wsum[8];

    int b    = blockIdx.x & 7;               // XCD-batch affinity
    int rb   = blockIdx.x >> 3;              // 0..63
    int base = rb * R_BLK;
    int band_lo = min(max(base - 5, 0), HH - BAND);

    const float* tg0 = vf_true + (size_t)b * 2 * HW;
    const float* tg1 = tg0 + HW;
    const float* pg0 = vf_pred + (size_t)b * 2 * HW;
    const float* pg1 = pg0 + HW;

    // ---- stage BAND rows of both fields into LDS as half2, coalesced ----
    for (int i = threadIdx.x; i < BAND * 128; i += 512) {
        int rl = i >> 7;                     // 0..18
        int g  = i & 127;                    // 4-px group
        int off = (band_lo + rl) * WW + g * 4;
        f4a tx = *(const f4a*)(tg0 + off);
        f4a ty = *(const f4a*)(tg1 + off);
        f4a px = *(const f4a*)(pg0 + off);
        f4a py = *(const f4a*)(pg1 + off);
        u4a wt = { f2h(tx.x, ty.x), f2h(tx.y, ty.y), f2h(tx.z, ty.z), f2h(tx.w, ty.w) };
        u4a wp = { f2h(px.x, py.x), f2h(px.y, py.y), f2h(px.z, py.z), f2h(px.w, py.w) };
        *(u4a*)&lt[rl * LSW + g * 4] = wt;
        *(u4a*)&lp[rl * LSW + g * 4] = wp;
    }
    __syncthreads();

    // ---- per-thread: 8 chains (wave owns one row; x = lane + 64c) ----
    int lane = threadIdx.x & 63;
    int wv   = threadIdx.x >> 6;             // 0..7
    int row  = base + wv;
    float fy = (float)row;

    float ptx[8], pty[8], ppx[8], ppy[8];
    float sum = 0.0f;

    // step 1: exact integer grid -> direct LDS reads
    #pragma unroll
    for (int c = 0; c < 8; ++c) {
        int x  = lane + 64 * c;
        int li = (row - band_lo) * LSW + x;
        f2 vt = h2f(lt[li]);
        f2 vp = h2f(lp[li]);
        float fx = (float)x;
        ptx[c] = fmaf(DXS, vt.x, fx);  pty[c] = fmaf(DXS, vt.y, fy);
        ppx[c] = fmaf(DXS, vp.x, fx);  ppy[c] = fmaf(DXS, vp.y, fy);
        float dx = ptx[c] - ppx[c], dy = pty[c] - ppy[c];
        sum += dx * dx + dy * dy;
    }

    // steps 2..8: LDS gathers
    #pragma unroll 1
    for (int s = 1; s < NSTEPS; ++s) {
        #pragma unroll
        for (int c = 0; c < 8; ++c) {
            f2 vt = bilin_lds(lt, band_lo, tg0, tg1, ptx[c], pty[c]);
            f2 vp = bilin_lds(lp, band_lo, pg0, pg1, ppx[c], ppy[c]);
            ptx[c] += DXS * vt.x;  pty[c] += DXS * vt.y;
            ppx[c] += DXS * vp.x;  ppy[c] += DXS * vp.y;
            float dx = ptx[c] - ppx[c], dy = pty[c] - ppy[c];
            sum += dx * dx + dy * dy;
        }
    }

    // ---- reduce + fused finalize ----
    for (int off = 32; off > 0; off >>= 1)
        sum += __shfl_down(sum, off, 64);
    if (lane == 0) wsum[wv] = sum;
    __syncthreads();
    if (threadIdx.x == 0) {
        double blocksum = 0.0;
        #pragma unroll
        for (int w = 0; w < 8; ++w) blocksum += (double)wsum[w];
        atomicAdd(acc, blocksum);
        __threadfence();
        unsigned int done = atomicAdd(cnt, 1u);
        if (done == (unsigned)(nblocks - 1)) {
            double total = atomicAdd(acc, 0.0);   // device-scope read-back
            const double n = (double)(NSTEPS + 1) * BB * 2 * HW;
            out[0] = (float)(total / n);
        }
    }
}

extern "C" void kernel_launch(void* const* d_in, const int* in_sizes, int n_in,
                              void* d_out, int out_size, void* d_ws, size_t ws_size,
                              hipStream_t stream) {
    const float* vf_pred = (const float*)d_in[0];
    const float* vf_true = (const float*)d_in[1];
    float* out = (float*)d_out;
    double* acc = (double*)d_ws;
    unsigned int* cnt = (unsigned int*)((char*)d_ws + 8);

    hipMemsetAsync(d_ws, 0, 16, stream);

    int blocks = BB * (HH / R_BLK);          // 8 * 64 = 512
    ivp_loss_lds<<<blocks, 512, 0, stream>>>(vf_pred, vf_true, acc, cnt, out, blocks);
}

// Round 12
// 49.463 us; speedup vs baseline: 1.3167x; 1.0034x over previous
//
#include <hip/hip_runtime.h>
#include <hip/hip_fp16.h>

#define HH 512
#define WW 512
#define BB 8
#define HW (HH * WW)
#define DXS 0.5f
#define NSTEPS 8

#define R_BLK 8          // trajectory rows per block (one per wave, 512 threads)
#define BAND 19          // staged rows per field (rows base-5 .. base+13)
#define LSW 512          // LDS row stride in u32

#define XCLAMP 510.99997f   // floor() <= 510 guaranteed, single med3 clamp

typedef float f2  __attribute__((ext_vector_type(2)));
typedef float f4a __attribute__((ext_vector_type(4)));
typedef unsigned int u4a __attribute__((ext_vector_type(4)));
typedef unsigned int u2l __attribute__((ext_vector_type(2), aligned(4)));  // -> ds_read2_b32

__device__ __forceinline__ f2 h2f(unsigned int h) {
    __half2 v = __builtin_bit_cast(__half2, h);
    float2 f = __half22float2(v);
    return (f2){f.x, f.y};
}
__device__ __forceinline__ unsigned int f2h(float a, float b) {
    __half2 h = __floats2half2_rn(a, b);
    return __builtin_bit_cast(unsigned int, h);
}

// bilinear from LDS half2 band: fp16 STORAGE, f32 lerp math (fp16 math fails
// correctness: chaotic trajectory amplification + squared-loss rectification).
// Rare global-f32 fallback for out-of-band y.
__device__ __forceinline__ f2 bilin_lds(const unsigned int* __restrict__ lds,
                                        int band_lo,
                                        const float* __restrict__ g0,
                                        const float* __restrict__ g1,
                                        float px, float py) {
    float x = fminf(fmaxf(px, 0.0f), XCLAMP);    // v_med3_f32
    float y = fminf(fmaxf(py, 0.0f), XCLAMP);
    float x0f = floorf(x);
    float y0f = floorf(y);
    float wx = x - x0f;
    float wy = y - y0f;
    int xi = (int)x0f;
    int yi = (int)y0f;
    int r = yi - band_lo;
    f2 out;
    if ((unsigned)r <= (unsigned)(BAND - 2)) {
        int idx = (r << 9) + xi;                  // r*LSW + xi
        u2l tw = *(const u2l*)&lds[idx];          // ds_read2_b32
        u2l bw = *(const u2l*)&lds[idx + LSW];
        f2 v00 = h2f(tw.x), v01 = h2f(tw.y);
        f2 v10 = h2f(bw.x), v11 = h2f(bw.y);
        f2 top = v00 + wx * (v01 - v00);
        f2 bot = v10 + wx * (v11 - v10);
        out = top + wy * (bot - top);
    } else {
        int i00 = yi * WW + xi;
        float w00 = (1.0f - wx) * (1.0f - wy);
        float w01 = wx * (1.0f - wy);
        float w10 = (1.0f - wx) * wy;
        float w11 = wx * wy;
        out.x = g0[i00] * w00 + g0[i00 + 1] * w01 + g0[i00 + WW] * w10 + g0[i00 + WW + 1] * w11;
        out.y = g1[i00] * w00 + g1[i00 + 1] * w01 + g1[i00 + WW] * w10 + g1[i00 + WW + 1] * w11;
    }
    return out;
}

__global__ __launch_bounds__(512, 4) void ivp_loss_lds(const float* __restrict__ vf_pred,
                                                       const float* __restrict__ vf_true,
                                                       double* __restrict__ acc,
                                                       unsigned int* __restrict__ cnt,
                                                       float* __restrict__ out,
                                                       int nblocks) {
    __shared__ unsigned int lt[BAND * LSW];   // true field, half2/px  (38 KiB)
    __shared__ unsigned int lp[BAND * LSW];   // pred field, half2/px  (38 KiB)
    __shared__ float wsum[8];

    int b    = blockIdx.x & 7;               // XCD-batch affinity
    int rb   = blockIdx.x >> 3;              // 0..63
    int base = rb * R_BLK;
    int band_lo = min(max(base - 5, 0), HH - BAND);

    const float* tg0 = vf_true + (size_t)b * 2 * HW;
    const float* tg1 = tg0 + HW;
    const float* pg0 = vf_pred + (size_t)b * 2 * HW;
    const float* pg1 = pg0 + HW;

    // ---- stage BAND rows of both fields into LDS as half2, coalesced ----
    for (int i = threadIdx.x; i < BAND * 128; i += 512) {
        int rl = i >> 7;                     // 0..18
        int g  = i & 127;                    // 4-px group
        int off = (band_lo + rl) * WW + g * 4;
        f4a tx = *(const f4a*)(tg0 + off);
        f4a ty = *(const f4a*)(tg1 + off);
        f4a px = *(const f4a*)(pg0 + off);
        f4a py = *(const f4a*)(pg1 + off);
        u4a wt = { f2h(tx.x, ty.x), f2h(tx.y, ty.y), f2h(tx.z, ty.z), f2h(tx.w, ty.w) };
        u4a wp = { f2h(px.x, py.x), f2h(px.y, py.y), f2h(px.z, py.z), f2h(px.w, py.w) };
        *(u4a*)&lt[rl * LSW + g * 4] = wt;
        *(u4a*)&lp[rl * LSW + g * 4] = wp;
    }
    __syncthreads();

    // ---- per-thread: 8 chains (wave owns one row; x = lane + 64c) ----
    int lane = threadIdx.x & 63;
    int wv   = threadIdx.x >> 6;             // 0..7
    int row  = base + wv;
    float fy = (float)row;

    float ptx[8], pty[8], ppx[8], ppy[8];
    float sum = 0.0f;

    // step 1: exact integer grid -> direct LDS reads
    #pragma unroll
    for (int c = 0; c < 8; ++c) {
        int x  = lane + 64 * c;
        int li = (row - band_lo) * LSW + x;
        f2 vt = h2f(lt[li]);
        f2 vp = h2f(lp[li]);
        float fx = (float)x;
        ptx[c] = fmaf(DXS, vt.x, fx);  pty[c] = fmaf(DXS, vt.y, fy);
        ppx[c] = fmaf(DXS, vp.x, fx);  ppy[c] = fmaf(DXS, vp.y, fy);
        float dx = ptx[c] - ppx[c], dy = pty[c] - ppy[c];
        sum += dx * dx + dy * dy;
    }

    // steps 2..8: LDS gathers
    #pragma unroll 1
    for (int s = 1; s < NSTEPS; ++s) {
        #pragma unroll
        for (int c = 0; c < 8; ++c) {
            f2 vt = bilin_lds(lt, band_lo, tg0, tg1, ptx[c], pty[c]);
            f2 vp = bilin_lds(lp, band_lo, pg0, pg1, ppx[c], ppy[c]);
            ptx[c] += DXS * vt.x;  pty[c] += DXS * vt.y;
            ppx[c] += DXS * vp.x;  ppy[c] += DXS * vp.y;
            float dx = ptx[c] - ppx[c], dy = pty[c] - ppy[c];
            sum += dx * dx + dy * dy;
        }
    }

    // ---- reduce + fused finalize ----
    for (int off = 32; off > 0; off >>= 1)
        sum += __shfl_down(sum, off, 64);
    if (lane == 0) wsum[wv] = sum;
    __syncthreads();
    if (threadIdx.x == 0) {
        double blocksum = 0.0;
        #pragma unroll
        for (int w = 0; w < 8; ++w) blocksum += (double)wsum[w];
        atomicAdd(acc, blocksum);
        __threadfence();
        unsigned int done = atomicAdd(cnt, 1u);
        if (done == (unsigned)(nblocks - 1)) {
            double total = atomicAdd(acc, 0.0);   // device-scope read-back
            const double n = (double)(NSTEPS + 1) * BB * 2 * HW;
            out[0] = (float)(total / n);
        }
    }
}

extern "C" void kernel_launch(void* const* d_in, const int* in_sizes, int n_in,
                              void* d_out, int out_size, void* d_ws, size_t ws_size,
                              hipStream_t stream) {
    const float* vf_pred = (const float*)d_in[0];
    const float* vf_true = (const float*)d_in[1];
    float* out = (float*)d_out;
    double* acc = (double*)d_ws;
    unsigned int* cnt = (unsigned int*)((char*)d_ws + 8);

    hipMemsetAsync(d_ws, 0, 16, stream);

    int blocks = BB * (HH / R_BLK);          // 8 * 64 = 512
    ivp_loss_lds<<<blocks, 512, 0, stream>>>(vf_pred, vf_true, acc, cnt, out, blocks);
}